// Round 1
// baseline (273.794 us; speedup 1.0000x reference)
//
#include <hip/hip_runtime.h>

// Problem constants (from setup_inputs): B=16, C=256, H=96, W=96, REP_K=3
#define B_    16
#define C_    256
#define HH    96
#define WW    96
#define W4    24          // WW / 4 float4 columns
#define TYN   8           // h-groups
#define HPT   12          // h values per thread (HH / TYN)
#define TPB   (W4 * TYN)  // 192 threads = 3 waves

// Fused circular depthwise conv along H:
// out[b,c,h,w] = sum_j eff_w[c,(j-h)%96] * (x+meta_pe)[b,c,j,w] + bias[c]
// eff_w[c,k] = weight[c,k] + (k<3 ? rep_weight[c,k] : 0)
__global__ __launch_bounds__(TPB, 3) void fused_circ_conv(
    const float* __restrict__ x,
    const float* __restrict__ meta_pe,
    const float* __restrict__ weight,
    const float* __restrict__ bias,
    const float* __restrict__ rep_weight,
    float* __restrict__ out)
{
    __shared__ float sX[HH * WW];     // 36 KB tile, row-major [h][w], meta_pe folded in
    __shared__ float sWext[2 * HH];   // eff_w doubled: sWext[t] = eff_w[t % 96]

    const int tid = threadIdx.x;
    const int blk = blockIdx.x;       // blk = b*256 + c
    const int c = blk & (C_ - 1);

    const size_t base = (size_t)blk * (HH * WW);
    const float4* __restrict__ xg4 = (const float4*)(x + base);

    // --- stage effective weights (192 entries, one per thread) ---
    {
        int k = (tid < HH) ? tid : (tid - HH);
        float wv = weight[c * HH + k];
        if (k < 3) wv += rep_weight[c * 3 + k];
        sWext[tid] = wv;
    }

    // --- stage X tile with meta_pe added (2304 float4 = 192 threads x 12) ---
    {
        float4* sX4 = (float4*)sX;
        const float* mp = meta_pe + c * HH;
#pragma unroll
        for (int r = 0; r < 12; ++r) {
            int i = tid + TPB * r;
            float4 v = xg4[i];
            float m = mp[i / W4];          // meta_pe depends only on row h = i/24
            v.x += m; v.y += m; v.z += m; v.w += m;
            sX4[i] = v;
        }
    }
    __syncthreads();

    const int tx = tid % W4;      // w-quad
    const int ty = tid / W4;      // h-group
    const int h0 = ty * HPT;

    float4 acc[HPT];
#pragma unroll
    for (int i = 0; i < HPT; ++i) acc[i] = make_float4(0.f, 0.f, 0.f, 0.f);

    // Sliding window of 12 weights in registers.
    // Invariant: at iteration j, win[(j-i) mod 12] == sWext[96 + (j-i) - h0],
    // which is exactly the weight for accumulator i: eff_w[(j - (h0+i)) mod 96].
    float win[12];
#pragma unroll
    for (int t = 1; t < 12; ++t) win[t] = sWext[84 + t - h0];  // preload m = t-12 in [-11,-1]

    const float4* __restrict__ xrow = (const float4*)sX + tx;
    const float* __restrict__ wrow = sWext + (96 - h0);

    for (int jj = 0; jj < 96; jj += 12) {
#pragma unroll
        for (int r = 0; r < 12; ++r) {
            const int j = jj + r;
            win[r] = wrow[j];                 // win[j % 12] = sWext[96 + j - h0]
            float4 xv = xrow[j * W4];         // X[j][4*tx .. 4*tx+3] (broadcast over ty)
#pragma unroll
            for (int i = 0; i < HPT; ++i) {
                float wv = win[(r - i + 12) % 12];   // compile-time index after unroll
                acc[i].x += wv * xv.x;
                acc[i].y += wv * xv.y;
                acc[i].z += wv * xv.z;
                acc[i].w += wv * xv.w;
            }
        }
    }

    // --- epilogue: add bias, store coalesced ---
    const float bv = bias[c];
    float4* og4 = (float4*)(out + base);
#pragma unroll
    for (int i = 0; i < HPT; ++i) {
        float4 v = acc[i];
        v.x += bv; v.y += bv; v.z += bv; v.w += bv;
        og4[(h0 + i) * W4 + tx] = v;
    }
}

extern "C" void kernel_launch(void* const* d_in, const int* in_sizes, int n_in,
                              void* d_out, int out_size, void* d_ws, size_t ws_size,
                              hipStream_t stream) {
    const float* x          = (const float*)d_in[0];
    const float* meta_pe    = (const float*)d_in[1];
    const float* weight     = (const float*)d_in[2];
    const float* bias       = (const float*)d_in[3];
    const float* rep_weight = (const float*)d_in[4];
    float* out = (float*)d_out;

    fused_circ_conv<<<dim3(B_ * C_), dim3(TPB), 0, stream>>>(
        x, meta_pe, weight, bias, rep_weight, out);
}